// Round 7
// baseline (1381.725 us; speedup 1.0000x reference)
//
#include <hip/hip_runtime.h>
#include <hip/hip_bf16.h>

#define FEAT 128
#define BINW 128            // nodes per coarse bin (power of 2)
#define BINSHIFT 7
#define TB 8192             // edges per tile in hist/scatter
#define MAXBIN 1024
#define MAXTILE 256         // bin_scan handles up to 256 tiles

__device__ __forceinline__ unsigned short f2b(float f) {
    __hip_bfloat16 h = __float2bfloat16(f);   // RNE
    return *reinterpret_cast<unsigned short*>(&h);
}
__device__ __forceinline__ float b2f(unsigned int u16) {
    unsigned int x = u16 << 16;
    float f;
    __builtin_memcpy(&f, &x, 4);
    return f;
}
__device__ __forceinline__ unsigned int pack2(float lo, float hi) {
    return (unsigned int)f2b(lo) | ((unsigned int)f2b(hi) << 16);
}

// ===========================================================================
// MAIN PATH: two-level binning (all atomics LDS-scope) + per-bin LDS gather
// ===========================================================================

// K1: feat16[row] = bf16(weight[row] * cj[row]); 8 feats/thread
__global__ void convert_kernel(const float* __restrict__ weight,
                               const float* __restrict__ cj,
                               unsigned short* __restrict__ feat16, int N) {
    int i = blockIdx.x * 256 + threadIdx.x;
    if (i >= N * (FEAT / 8)) return;
    int row = i >> 4;
    int seg = i & 15;
    float c = cj[row];
    const float4* p = reinterpret_cast<const float4*>(weight + (size_t)row * FEAT + seg * 8);
    float4 a = p[0], b = p[1];
    uint4 o;
    o.x = pack2(a.x * c, a.y * c);
    o.y = pack2(a.z * c, a.w * c);
    o.z = pack2(b.x * c, b.y * c);
    o.w = pack2(b.z * c, b.w * c);
    *reinterpret_cast<uint4*>(feat16 + (size_t)i * 8) = o;
}

// K2: per-tile coarse-bin histogram -> cnt[tile][bin]
__global__ void hist_bins_kernel(const int* __restrict__ dst, int* __restrict__ cnt,
                                 int E, int NBIN) {
    __shared__ int h[MAXBIN];
    int tile = blockIdx.x;
    for (int b = threadIdx.x; b < NBIN; b += 256) h[b] = 0;
    __syncthreads();
    int e0 = tile * TB;
    #pragma unroll 4
    for (int i = 0; i < TB / 256; ++i) {
        int e = e0 + i * 256 + threadIdx.x;
        if (e < E) atomicAdd(&h[dst[e] >> BINSHIFT], 1);
    }
    __syncthreads();
    for (int b = threadIdx.x; b < NBIN; b += 256) cnt[tile * NBIN + b] = h[b];
}

// K3a: one block per bin: exclusive scan of cnt[*][bin] over tiles ->
//      base_local[tile][bin]; also binTot[bin]. NBIN-way parallel.
__global__ void bin_scan_kernel(const int* __restrict__ cnt, int* __restrict__ base_local,
                                int* __restrict__ binTot, int NBIN, int NTILE) {
    __shared__ int s[MAXTILE];
    int b = blockIdx.x;
    int t = threadIdx.x;              // block = 256 = MAXTILE
    int v = (t < NTILE) ? cnt[(size_t)t * NBIN + b] : 0;
    s[t] = v;
    __syncthreads();
    for (int off = 1; off < MAXTILE; off <<= 1) {
        int u = (t >= off) ? s[t - off] : 0;
        __syncthreads();
        s[t] += u;
        __syncthreads();
    }
    if (t < NTILE) base_local[(size_t)t * NBIN + b] = s[t] - v;   // exclusive
    if (t == MAXTILE - 1) binTot[b] = s[t];                       // inclusive total
}

// K3b: single-block exclusive scan of binTot[NBIN] -> binStart[0..NBIN]
__global__ void scan_tot_kernel(const int* __restrict__ binTot, int* __restrict__ binStart,
                                int NBIN) {
    __shared__ int s[1024];
    int t = threadIdx.x;
    int v = (t < NBIN) ? binTot[t] : 0;
    s[t] = v;
    __syncthreads();
    for (int off = 1; off < 1024; off <<= 1) {
        int u = (t >= off) ? s[t - off] : 0;
        __syncthreads();
        s[t] += u;
        __syncthreads();
    }
    if (t < NBIN) binStart[t] = s[t] - v;
    if (t == NBIN - 1) binStart[NBIN] = s[t];
}

// K4: scatter packed (src | local_dst<<17) into coarse-bin-grouped order.
// LDS cursors only; global writes land in NBIN contiguous regions.
__global__ void scatter_pairs_kernel(const int* __restrict__ src, const int* __restrict__ dst,
                                     const int* __restrict__ base_local,
                                     const int* __restrict__ binStart,
                                     unsigned* __restrict__ pair,
                                     int E, int NBIN) {
    __shared__ int base_l[MAXBIN];
    __shared__ int cur[MAXBIN];
    int tile = blockIdx.x;
    for (int b = threadIdx.x; b < NBIN; b += 256) {
        base_l[b] = binStart[b] + base_local[(size_t)tile * NBIN + b];
        cur[b] = 0;
    }
    __syncthreads();
    int e0 = tile * TB;
    #pragma unroll 4
    for (int i = 0; i < TB / 256; ++i) {
        int e = e0 + i * 256 + threadIdx.x;
        if (e < E) {
            int d = dst[e];
            int b = d >> BINSHIFT;
            int pos = atomicAdd(&cur[b], 1);
            pair[base_l[b] + pos] = (unsigned)src[e] | ((unsigned)(d & (BINW - 1)) << 17);
        }
    }
}

// K5: one 1024-thread block per bin; 128x128 f32 accumulator in 64 KB LDS
// (2 blocks/CU). Each of 16 waves strides the bin's edge list: wave-uniform
// pair[k] load (HW broadcast), one u32/lane = full 256 B bf16 row, 2 VALU
// converts, 2 LDS atomicAdd (ds_add_f32, no return). De-interleaved feature
// layout perm(f) = (f&1)*64 + (f>>1): both ds_adds hit bank lane&31 ->
// 2 lanes/bank (free). Epilogue scales by ci and writes each row once.
__global__ void __launch_bounds__(1024)
bin_gather_kernel(const unsigned* __restrict__ feat32,
                  const float* __restrict__ ci,
                  const int* __restrict__ binStart,
                  const unsigned* __restrict__ pair,
                  float* __restrict__ out, int N) {
    __shared__ float acc[BINW * FEAT];   // exactly 64 KB
    float4* a4 = reinterpret_cast<float4*>(acc);
    for (int i = threadIdx.x; i < BINW * FEAT / 4; i += 1024)
        a4[i] = make_float4(0.f, 0.f, 0.f, 0.f);
    __syncthreads();

    int bin = blockIdx.x;
    int start = binStart[bin];
    int end   = binStart[bin + 1];
    int w    = threadIdx.x >> 6;         // wave 0..15
    int lane = threadIdx.x & 63;

    #pragma unroll 4
    for (int k = start + w; k < end; k += 16) {
        unsigned p = pair[k];                              // wave-uniform
        int s  = p & 0x1FFFF;
        int ld = p >> 17;
        unsigned u = feat32[((size_t)s << 6) + lane];      // feats (2*lane, 2*lane+1)
        unsigned lo = u << 16;
        unsigned hi = u & 0xFFFF0000u;
        float flo, fhi;
        __builtin_memcpy(&flo, &lo, 4);
        __builtin_memcpy(&fhi, &hi, 4);
        atomicAdd(&acc[(ld << 7) + lane],      flo);       // feat 2*lane
        atomicAdd(&acc[(ld << 7) + 64 + lane], fhi);       // feat 2*lane+1
    }
    __syncthreads();

    // epilogue: out[node][f] = acc[nl*128 + (f&1)*64 + (f>>1)] * ci[node]
    for (int r = 0; r < 4; ++r) {
        int g = threadIdx.x + (r << 10);     // 0..4095 float4 groups
        int nl = g >> 5;
        int q  = g & 31;
        int node = (bin << BINSHIFT) + nl;
        if (node < N) {
            float c = ci[node];
            int b = nl << 7;
            float4 v;
            v.x = acc[b + 2 * q]          * c;
            v.y = acc[b + 64 + 2 * q]     * c;
            v.z = acc[b + 2 * q + 1]      * c;
            v.w = acc[b + 64 + 2 * q + 1] * c;
            *reinterpret_cast<float4*>(out + ((size_t)node << 7) + (q << 2)) = v;
        }
    }
}

// ===========================================================================
// MID TIER (round-3 verified): per-node CSR + bf16 gather
// ===========================================================================

__global__ void zero_ints_kernel(int* __restrict__ p, int n) {
    int i = blockIdx.x * blockDim.x + threadIdx.x;
    if (i < n) p[i] = 0;
}

__global__ void convert_hist_kernel(const float* __restrict__ weight,
                                    const float* __restrict__ cj,
                                    const int* __restrict__ dst,
                                    int* __restrict__ counts,
                                    unsigned short* __restrict__ feat16,
                                    int N, int E) {
    int i = blockIdx.x * blockDim.x + threadIdx.x;
    int NC = N * (FEAT / 8);
    if (i < NC) {
        int row = i >> 4;
        int seg = i & 15;
        float c = cj[row];
        const float4* p = reinterpret_cast<const float4*>(weight + (size_t)row * FEAT + seg * 8);
        float4 a = p[0], b = p[1];
        uint4 o;
        o.x = pack2(a.x * c, a.y * c);
        o.y = pack2(a.z * c, a.w * c);
        o.z = pack2(b.x * c, b.y * c);
        o.w = pack2(b.z * c, b.w * c);
        *reinterpret_cast<uint4*>(feat16 + (size_t)i * 8) = o;
    }
    if (i < E) atomicAdd(&counts[dst[i]], 1);
}

__global__ void block_sum_kernel(const int* __restrict__ counts, int* __restrict__ bsum, int N) {
    __shared__ int s[256];
    int i = blockIdx.x * 256 + threadIdx.x;
    s[threadIdx.x] = (i < N) ? counts[i] : 0;
    __syncthreads();
    for (int off = 128; off > 0; off >>= 1) {
        if (threadIdx.x < off) s[threadIdx.x] += s[threadIdx.x + off];
        __syncthreads();
    }
    if (threadIdx.x == 0) bsum[blockIdx.x] = s[0];
}

__global__ void scan_bsum_kernel(int* __restrict__ bsum, int nb) {
    __shared__ int s[512];
    int t = threadIdx.x;
    int mine = (t < nb) ? bsum[t] : 0;
    s[t] = mine;
    __syncthreads();
    for (int off = 1; off < 512; off <<= 1) {
        int v = (t >= off) ? s[t - off] : 0;
        __syncthreads();
        s[t] += v;
        __syncthreads();
    }
    if (t < nb) bsum[t] = s[t] - mine;
}

__global__ void scan_counts_kernel(const int* __restrict__ counts, const int* __restrict__ bsum,
                                   int* __restrict__ offsets, int* __restrict__ cursor,
                                   int N, int E) {
    __shared__ int s[256];
    int t = threadIdx.x;
    int i = blockIdx.x * 256 + t;
    int mine = (i < N) ? counts[i] : 0;
    s[t] = mine;
    __syncthreads();
    for (int off = 1; off < 256; off <<= 1) {
        int v = (t >= off) ? s[t - off] : 0;
        __syncthreads();
        s[t] += v;
        __syncthreads();
    }
    if (i < N) {
        int o = bsum[blockIdx.x] + s[t] - mine;
        offsets[i] = o;
        cursor[i] = o;
    }
    if (i == 0 && blockIdx.x == 0) offsets[N] = E;
}

__global__ void bucket_kernel(const int* __restrict__ src, const int* __restrict__ dst,
                              int* __restrict__ cursor,
                              int* __restrict__ src_sorted, int E) {
    int i = blockIdx.x * blockDim.x + threadIdx.x;
    if (i < E) {
        int pos = atomicAdd(&cursor[dst[i]], 1);
        src_sorted[pos] = src[i];
    }
}

__global__ void gather_kernel(const unsigned short* __restrict__ feat16,
                              const float* __restrict__ ci,
                              const int* __restrict__ offsets,
                              const int* __restrict__ src_sorted,
                              float* __restrict__ out, int N) {
    int gt = blockIdx.x * blockDim.x + threadIdx.x;
    int node = gt >> 6;
    if (node >= N) return;
    int lane = gt & 63;
    int fi   = (lane & 31) << 2;
    int half = lane >> 5;
    int start = offsets[node];
    int end   = offsets[node + 1];
    float4 acc = make_float4(0.f, 0.f, 0.f, 0.f);
    #pragma unroll 2
    for (int k = start + half; k < end; k += 2) {
        int s = src_sorted[k];
        ushort4 wv = *reinterpret_cast<const ushort4*>(feat16 + (size_t)s * FEAT + fi);
        acc.x += b2f(wv.x);
        acc.y += b2f(wv.y);
        acc.z += b2f(wv.z);
        acc.w += b2f(wv.w);
    }
    acc.x += __shfl_xor(acc.x, 32);
    acc.y += __shfl_xor(acc.y, 32);
    acc.z += __shfl_xor(acc.z, 32);
    acc.w += __shfl_xor(acc.w, 32);
    if (half == 0) {
        float c = ci[node];
        float4 r = make_float4(acc.x * c, acc.y * c, acc.z * c, acc.w * c);
        *reinterpret_cast<float4*>(out + (size_t)node * FEAT + fi) = r;
    }
}

// ===========================================================================
// LAST TIER (round-1 verified): float atomics
// ===========================================================================

__global__ void gcmc_zero_kernel(float4* __restrict__ out, int n4) {
    int i = blockIdx.x * blockDim.x + threadIdx.x;
    if (i < n4) out[i] = make_float4(0.f, 0.f, 0.f, 0.f);
}

__global__ void gcmc_scatter_kernel(const float* __restrict__ weight,
                                    const float* __restrict__ cj,
                                    const int* __restrict__ src,
                                    const int* __restrict__ dst,
                                    float* __restrict__ out,
                                    int n_edges) {
    int t = blockIdx.x * blockDim.x + threadIdx.x;
    int e = t >> 5;
    int f = (t & 31) << 2;
    if (e >= n_edges) return;
    int s = src[e];
    int d = dst[e];
    float c = cj[s];
    const float4 w = *reinterpret_cast<const float4*>(weight + (size_t)s * FEAT + f);
    float* o = out + (size_t)d * FEAT + f;
    unsafeAtomicAdd(o + 0, w.x * c);
    unsafeAtomicAdd(o + 1, w.y * c);
    unsafeAtomicAdd(o + 2, w.z * c);
    unsafeAtomicAdd(o + 3, w.w * c);
}

__global__ void gcmc_scale_kernel(float4* __restrict__ out,
                                  const float* __restrict__ ci, int n4) {
    int i = blockIdx.x * blockDim.x + threadIdx.x;
    if (i < n4) {
        float c = ci[i >> 5];
        float4 v = out[i];
        v.x *= c; v.y *= c; v.z *= c; v.w *= c;
        out[i] = v;
    }
}

// ===========================================================================

static inline size_t align256(size_t x) { return (x + 255) & ~(size_t)255; }

extern "C" void kernel_launch(void* const* d_in, const int* in_sizes, int n_in,
                              void* d_out, int out_size, void* d_ws, size_t ws_size,
                              hipStream_t stream) {
    const float* weight = (const float*)d_in[0];
    const float* cj     = (const float*)d_in[1];
    const float* ci     = (const float*)d_in[2];
    const int*   src    = (const int*)d_in[3];
    const int*   dst    = (const int*)d_in[4];
    float* out = (float*)d_out;

    const int N = in_sizes[1];             // cj is [N,1]
    const int E = in_sizes[3];

    const int NBIN  = (N + BINW - 1) >> BINSHIFT;
    const int NTILE = (E + TB - 1) / TB;

    // --- main-path workspace layout ---
    size_t o_feat = 0;                                            // N*FEAT bf16
    size_t o_pair = align256(o_feat + (size_t)N * FEAT * 2);      // E u32
    size_t o_cnt  = align256(o_pair + (size_t)E * 4);             // NTILE*NBIN int
    size_t o_base = align256(o_cnt + (size_t)NTILE * NBIN * 4);   // NTILE*NBIN int
    size_t o_tot  = align256(o_base + (size_t)NTILE * NBIN * 4);  // NBIN int
    size_t o_bs   = align256(o_tot + (size_t)NBIN * 4);           // NBIN+1 int
    size_t need_new = o_bs + (size_t)(NBIN + 1) * 4;

    if (ws_size >= need_new && NBIN <= MAXBIN && NTILE <= MAXTILE && N <= (1 << 17)) {
        char* ws = (char*)d_ws;
        unsigned short* feat16 = (unsigned short*)(ws + o_feat);
        unsigned* pair   = (unsigned*)(ws + o_pair);
        int* cnt         = (int*)(ws + o_cnt);
        int* base_local  = (int*)(ws + o_base);
        int* binTot      = (int*)(ws + o_tot);
        int* binStart    = (int*)(ws + o_bs);

        convert_kernel<<<(N * (FEAT / 8) + 255) / 256, 256, 0, stream>>>(
            weight, cj, feat16, N);
        hist_bins_kernel<<<NTILE, 256, 0, stream>>>(dst, cnt, E, NBIN);
        bin_scan_kernel<<<NBIN, MAXTILE, 0, stream>>>(cnt, base_local, binTot, NBIN, NTILE);
        scan_tot_kernel<<<1, 1024, 0, stream>>>(binTot, binStart, NBIN);
        scatter_pairs_kernel<<<NTILE, 256, 0, stream>>>(src, dst, base_local, binStart,
                                                        pair, E, NBIN);
        bin_gather_kernel<<<NBIN, 1024, 0, stream>>>((const unsigned*)feat16, ci,
                                                     binStart, pair, out, N);
        return;
    }

    // --- mid tier: round-3 CSR path ---
    const int NB = (N + 255) / 256;
    size_t m_off = 0;                                              // (N+1) int
    size_t m_cur = align256(m_off + (size_t)(N + 1) * 4);          // N int
    size_t m_bsm = align256(m_cur + (size_t)N * 4);                // 512 int
    size_t m_src = align256(m_bsm + 512 * 4);                      // E int
    size_t m_ft  = align256(m_src + (size_t)E * 4);                // N*FEAT bf16
    size_t need_mid = m_ft + (size_t)N * FEAT * 2;

    if (ws_size >= need_mid && NB <= 512) {
        char* ws = (char*)d_ws;
        int* offsets    = (int*)(ws + m_off);
        int* cursor     = (int*)(ws + m_cur);
        int* bsum       = (int*)(ws + m_bsm);
        int* src_sorted = (int*)(ws + m_src);
        unsigned short* feat16 = (unsigned short*)(ws + m_ft);

        zero_ints_kernel<<<NB, 256, 0, stream>>>(cursor, N);
        {
            long T = (long)N * (FEAT / 8);
            if ((long)E > T) T = E;
            convert_hist_kernel<<<(int)((T + 255) / 256), 256, 0, stream>>>(
                weight, cj, dst, cursor, feat16, N, E);
        }
        block_sum_kernel<<<NB, 256, 0, stream>>>(cursor, bsum, N);
        scan_bsum_kernel<<<1, 512, 0, stream>>>(bsum, NB);
        scan_counts_kernel<<<NB, 256, 0, stream>>>(cursor, bsum, offsets, cursor, N, E);
        bucket_kernel<<<(E + 255) / 256, 256, 0, stream>>>(src, dst, cursor, src_sorted, E);
        long threads = (long)N * 64;
        gather_kernel<<<(int)((threads + 255) / 256), 256, 0, stream>>>(
            feat16, ci, offsets, src_sorted, out, N);
        return;
    }

    // --- last tier: atomics ---
    const int total = N * FEAT;
    const int n4 = total >> 2;
    gcmc_zero_kernel<<<(n4 + 255) / 256, 256, 0, stream>>>((float4*)out, n4);
    const long threads = (long)E * 32;
    gcmc_scatter_kernel<<<(int)((threads + 255) / 256), 256, 0, stream>>>(
        weight, cj, src, dst, out, E);
    gcmc_scale_kernel<<<(n4 + 255) / 256, 256, 0, stream>>>((float4*)out, ci, n4);
}

// Round 8
// 132.129 us; speedup vs baseline: 10.4574x; 10.4574x over previous
//
#include <hip/hip_runtime.h>
#include <hip/hip_bf16.h>

#define FEAT 128
#define BINW 128            // nodes per coarse bin (power of 2)
#define BINSHIFT 7
#define TB 8192             // edges per tile in hist/scatter
#define MAXBIN 1024
#define MAXTILE 256         // bin_scan handles up to 256 tiles
#define FS_CAP 4096         // fine_sort LDS staging capacity (edges per bin)

__device__ __forceinline__ unsigned short f2b(float f) {
    __hip_bfloat16 h = __float2bfloat16(f);   // RNE
    return *reinterpret_cast<unsigned short*>(&h);
}
__device__ __forceinline__ float b2f_lo(unsigned u) {   // low ushort -> f32
    unsigned x = u << 16;
    float f;
    __builtin_memcpy(&f, &x, 4);
    return f;
}
__device__ __forceinline__ float b2f_hi(unsigned u) {   // high ushort -> f32
    unsigned x = u & 0xFFFF0000u;
    float f;
    __builtin_memcpy(&f, &x, 4);
    return f;
}
__device__ __forceinline__ unsigned int pack2(float lo, float hi) {
    return (unsigned int)f2b(lo) | ((unsigned int)f2b(hi) << 16);
}

// ===========================================================================
// MAIN PATH: two-level binning (all atomics LDS-scope) + per-node gather
// ===========================================================================

// K1: feat16[row] = bf16(weight[row] * cj[row]); 8 feats/thread
__global__ void convert_kernel(const float* __restrict__ weight,
                               const float* __restrict__ cj,
                               unsigned short* __restrict__ feat16, int N) {
    int i = blockIdx.x * 256 + threadIdx.x;
    if (i >= N * (FEAT / 8)) return;
    int row = i >> 4;
    int seg = i & 15;
    float c = cj[row];
    const float4* p = reinterpret_cast<const float4*>(weight + (size_t)row * FEAT + seg * 8);
    float4 a = p[0], b = p[1];
    uint4 o;
    o.x = pack2(a.x * c, a.y * c);
    o.y = pack2(a.z * c, a.w * c);
    o.z = pack2(b.x * c, b.y * c);
    o.w = pack2(b.z * c, b.w * c);
    *reinterpret_cast<uint4*>(feat16 + (size_t)i * 8) = o;
}

// K2: per-tile coarse-bin histogram -> cnt[tile][bin]
__global__ void hist_bins_kernel(const int* __restrict__ dst, int* __restrict__ cnt,
                                 int E, int NBIN) {
    __shared__ int h[MAXBIN];
    int tile = blockIdx.x;
    for (int b = threadIdx.x; b < NBIN; b += 256) h[b] = 0;
    __syncthreads();
    int e0 = tile * TB;
    #pragma unroll 4
    for (int i = 0; i < TB / 256; ++i) {
        int e = e0 + i * 256 + threadIdx.x;
        if (e < E) atomicAdd(&h[dst[e] >> BINSHIFT], 1);
    }
    __syncthreads();
    for (int b = threadIdx.x; b < NBIN; b += 256) cnt[tile * NBIN + b] = h[b];
}

// K3a: one block per bin: exclusive scan of cnt[*][bin] over tiles ->
//      base_local[tile][bin]; also binTot[bin]. NBIN-way parallel.
__global__ void bin_scan_kernel(const int* __restrict__ cnt, int* __restrict__ base_local,
                                int* __restrict__ binTot, int NBIN, int NTILE) {
    __shared__ int s[MAXTILE];
    int b = blockIdx.x;
    int t = threadIdx.x;              // block = 256 = MAXTILE
    int v = (t < NTILE) ? cnt[(size_t)t * NBIN + b] : 0;
    s[t] = v;
    __syncthreads();
    for (int off = 1; off < MAXTILE; off <<= 1) {
        int u = (t >= off) ? s[t - off] : 0;
        __syncthreads();
        s[t] += u;
        __syncthreads();
    }
    if (t < NTILE) base_local[(size_t)t * NBIN + b] = s[t] - v;   // exclusive
    if (t == MAXTILE - 1) binTot[b] = s[t];                       // inclusive total
}

// K3b: single-block exclusive scan of binTot[NBIN] -> binStart[0..NBIN]
__global__ void scan_tot_kernel(const int* __restrict__ binTot, int* __restrict__ binStart,
                                int NBIN) {
    __shared__ int s[1024];
    int t = threadIdx.x;
    int v = (t < NBIN) ? binTot[t] : 0;
    s[t] = v;
    __syncthreads();
    for (int off = 1; off < 1024; off <<= 1) {
        int u = (t >= off) ? s[t - off] : 0;
        __syncthreads();
        s[t] += u;
        __syncthreads();
    }
    if (t < NBIN) binStart[t] = s[t] - v;
    if (t == NBIN - 1) binStart[NBIN] = s[t];
}

// K4: scatter packed (src | local_dst<<17) into coarse-bin-grouped order.
// LDS cursors only; global writes land in NBIN contiguous regions.
__global__ void scatter_pairs_kernel(const int* __restrict__ src, const int* __restrict__ dst,
                                     const int* __restrict__ base_local,
                                     const int* __restrict__ binStart,
                                     unsigned* __restrict__ pair,
                                     int E, int NBIN) {
    __shared__ int base_l[MAXBIN];
    __shared__ int cur[MAXBIN];
    int tile = blockIdx.x;
    for (int b = threadIdx.x; b < NBIN; b += 256) {
        base_l[b] = binStart[b] + base_local[(size_t)tile * NBIN + b];
        cur[b] = 0;
    }
    __syncthreads();
    int e0 = tile * TB;
    #pragma unroll 4
    for (int i = 0; i < TB / 256; ++i) {
        int e = e0 + i * 256 + threadIdx.x;
        if (e < E) {
            int d = dst[e];
            int b = d >> BINSHIFT;
            int pos = atomicAdd(&cur[b], 1);
            pair[base_l[b] + pos] = (unsigned)src[e] | ((unsigned)(d & (BINW - 1)) << 17);
        }
    }
}

// K5: per-bin fine counting sort. One 256-thread block per bin (~2K edges,
// 128 local nodes). Common case: stages the segment in LDS (<= FS_CAP edges);
// oversize bins fall back to staging through `tmp` (= d_out as scratch, fully
// rewritten by the gather afterwards). Emits per-node CSR offsets and writes
// src values back into `pair` grouped by node. All atomics LDS-scope.
__global__ void fine_sort_kernel(unsigned* __restrict__ pair,
                                 unsigned* __restrict__ tmp,
                                 const int* __restrict__ binStart,
                                 int* __restrict__ offsets,
                                 int N, int E) {
    __shared__ int cnt[BINW];
    __shared__ int sbase[BINW];
    __shared__ unsigned stage[FS_CAP];
    int bin = blockIdx.x;
    int t = threadIdx.x;
    if (t < BINW) cnt[t] = 0;
    __syncthreads();
    int start = binStart[bin];
    int end   = binStart[bin + 1];
    bool lds_ok = (end - start) <= FS_CAP;

    if (lds_ok) {
        for (int k = start + t; k < end; k += 256) {
            unsigned p = pair[k];
            stage[k - start] = p;
            atomicAdd(&cnt[p >> 17], 1);
        }
    } else {
        for (int k = start + t; k < end; k += 256) {
            unsigned p = pair[k];
            tmp[k] = p;
            atomicAdd(&cnt[p >> 17], 1);
        }
    }
    __syncthreads();
    int mine = (t < BINW) ? cnt[t] : 0;
    if (t < BINW) sbase[t] = mine;
    __syncthreads();
    for (int d = 1; d < BINW; d <<= 1) {     // Hillis-Steele inclusive scan
        int v = 0;
        if (t < BINW && t >= d) v = sbase[t - d];
        __syncthreads();
        if (t < BINW) sbase[t] += v;
        __syncthreads();
    }
    if (t < BINW) {
        int excl = sbase[t] - mine;
        int node = (bin << BINSHIFT) + t;
        if (node < N) offsets[node] = start + excl;
        sbase[t] = start + excl;             // absolute base per local node
        cnt[t] = 0;                          // reuse as cursor
    }
    if (bin == 0 && t == 0) offsets[N] = E;
    __syncthreads();
    if (lds_ok) {
        for (int k = start + t; k < end; k += 256) {
            unsigned p = stage[k - start];
            int ld = p >> 17;
            int pos = atomicAdd(&cnt[ld], 1);
            pair[sbase[ld] + pos] = p & 0x1FFFF;
        }
    } else {
        for (int k = start + t; k < end; k += 256) {
            unsigned p = tmp[k];
            int ld = p >> 17;
            int pos = atomicAdd(&cnt[ld], 1);
            pair[sbase[ld] + pos] = p & 0x1FFFF;
        }
    }
}

// K6: one 64-lane wave per node, split as 4x16-lane groups; each group takes
// every 4th edge; each lane loads 16 B (8 bf16 feats) per edge -> 2x the
// in-flight requests and 2x bytes/request vs the 2x32 variant. Reduce with
// two shfl_xor levels; quarter 0 writes 32 B/lane.
__global__ void gather_kernel(const unsigned short* __restrict__ feat16,
                              const float* __restrict__ ci,
                              const int* __restrict__ offsets,
                              const int* __restrict__ src_sorted,
                              float* __restrict__ out, int N) {
    int gt = blockIdx.x * blockDim.x + threadIdx.x;
    int node = gt >> 6;
    if (node >= N) return;
    int lane = gt & 63;
    int fi   = (lane & 15) << 3;         // feature offset (0,8,...,120)
    int q    = lane >> 4;                // quarter 0..3
    int start = offsets[node];
    int end   = offsets[node + 1];
    float acc[8] = {0.f, 0.f, 0.f, 0.f, 0.f, 0.f, 0.f, 0.f};
    #pragma unroll 2
    for (int k = start + q; k < end; k += 4) {
        int s = src_sorted[k];
        uint4 u = *reinterpret_cast<const uint4*>(feat16 + ((size_t)s << 7) + fi);
        acc[0] += b2f_lo(u.x); acc[1] += b2f_hi(u.x);
        acc[2] += b2f_lo(u.y); acc[3] += b2f_hi(u.y);
        acc[4] += b2f_lo(u.z); acc[5] += b2f_hi(u.z);
        acc[6] += b2f_lo(u.w); acc[7] += b2f_hi(u.w);
    }
    #pragma unroll
    for (int j = 0; j < 8; ++j) {
        acc[j] += __shfl_xor(acc[j], 16);
        acc[j] += __shfl_xor(acc[j], 32);
    }
    if (q == 0) {
        float c = ci[node];
        float4 v0 = make_float4(acc[0] * c, acc[1] * c, acc[2] * c, acc[3] * c);
        float4 v1 = make_float4(acc[4] * c, acc[5] * c, acc[6] * c, acc[7] * c);
        float* o = out + ((size_t)node << 7) + fi;
        *reinterpret_cast<float4*>(o)     = v0;
        *reinterpret_cast<float4*>(o + 4) = v1;
    }
}

// ===========================================================================
// MID TIER (verified): per-node CSR + bf16 gather
// ===========================================================================

__global__ void zero_ints_kernel(int* __restrict__ p, int n) {
    int i = blockIdx.x * blockDim.x + threadIdx.x;
    if (i < n) p[i] = 0;
}

__global__ void convert_hist_kernel(const float* __restrict__ weight,
                                    const float* __restrict__ cj,
                                    const int* __restrict__ dst,
                                    int* __restrict__ counts,
                                    unsigned short* __restrict__ feat16,
                                    int N, int E) {
    int i = blockIdx.x * blockDim.x + threadIdx.x;
    int NC = N * (FEAT / 8);
    if (i < NC) {
        int row = i >> 4;
        int seg = i & 15;
        float c = cj[row];
        const float4* p = reinterpret_cast<const float4*>(weight + (size_t)row * FEAT + seg * 8);
        float4 a = p[0], b = p[1];
        uint4 o;
        o.x = pack2(a.x * c, a.y * c);
        o.y = pack2(a.z * c, a.w * c);
        o.z = pack2(b.x * c, b.y * c);
        o.w = pack2(b.z * c, b.w * c);
        *reinterpret_cast<uint4*>(feat16 + (size_t)i * 8) = o;
    }
    if (i < E) atomicAdd(&counts[dst[i]], 1);
}

__global__ void block_sum_kernel(const int* __restrict__ counts, int* __restrict__ bsum, int N) {
    __shared__ int s[256];
    int i = blockIdx.x * 256 + threadIdx.x;
    s[threadIdx.x] = (i < N) ? counts[i] : 0;
    __syncthreads();
    for (int off = 128; off > 0; off >>= 1) {
        if (threadIdx.x < off) s[threadIdx.x] += s[threadIdx.x + off];
        __syncthreads();
    }
    if (threadIdx.x == 0) bsum[blockIdx.x] = s[0];
}

__global__ void scan_bsum_kernel(int* __restrict__ bsum, int nb) {
    __shared__ int s[512];
    int t = threadIdx.x;
    int mine = (t < nb) ? bsum[t] : 0;
    s[t] = mine;
    __syncthreads();
    for (int off = 1; off < 512; off <<= 1) {
        int v = (t >= off) ? s[t - off] : 0;
        __syncthreads();
        s[t] += v;
        __syncthreads();
    }
    if (t < nb) bsum[t] = s[t] - mine;
}

__global__ void scan_counts_kernel(const int* __restrict__ counts, const int* __restrict__ bsum,
                                   int* __restrict__ offsets, int* __restrict__ cursor,
                                   int N, int E) {
    __shared__ int s[256];
    int t = threadIdx.x;
    int i = blockIdx.x * 256 + t;
    int mine = (i < N) ? counts[i] : 0;
    s[t] = mine;
    __syncthreads();
    for (int off = 1; off < 256; off <<= 1) {
        int v = (t >= off) ? s[t - off] : 0;
        __syncthreads();
        s[t] += v;
        __syncthreads();
    }
    if (i < N) {
        int o = bsum[blockIdx.x] + s[t] - mine;
        offsets[i] = o;
        cursor[i] = o;
    }
    if (i == 0 && blockIdx.x == 0) offsets[N] = E;
}

__global__ void bucket_kernel(const int* __restrict__ src, const int* __restrict__ dst,
                              int* __restrict__ cursor,
                              int* __restrict__ src_sorted, int E) {
    int i = blockIdx.x * blockDim.x + threadIdx.x;
    if (i < E) {
        int pos = atomicAdd(&cursor[dst[i]], 1);
        src_sorted[pos] = src[i];
    }
}

// ===========================================================================
// LAST TIER (round-1 verified): float atomics
// ===========================================================================

__global__ void gcmc_zero_kernel(float4* __restrict__ out, int n4) {
    int i = blockIdx.x * blockDim.x + threadIdx.x;
    if (i < n4) out[i] = make_float4(0.f, 0.f, 0.f, 0.f);
}

__global__ void gcmc_scatter_kernel(const float* __restrict__ weight,
                                    const float* __restrict__ cj,
                                    const int* __restrict__ src,
                                    const int* __restrict__ dst,
                                    float* __restrict__ out,
                                    int n_edges) {
    int t = blockIdx.x * blockDim.x + threadIdx.x;
    int e = t >> 5;
    int f = (t & 31) << 2;
    if (e >= n_edges) return;
    int s = src[e];
    int d = dst[e];
    float c = cj[s];
    const float4 w = *reinterpret_cast<const float4*>(weight + (size_t)s * FEAT + f);
    float* o = out + (size_t)d * FEAT + f;
    unsafeAtomicAdd(o + 0, w.x * c);
    unsafeAtomicAdd(o + 1, w.y * c);
    unsafeAtomicAdd(o + 2, w.z * c);
    unsafeAtomicAdd(o + 3, w.w * c);
}

__global__ void gcmc_scale_kernel(float4* __restrict__ out,
                                  const float* __restrict__ ci, int n4) {
    int i = blockIdx.x * blockDim.x + threadIdx.x;
    if (i < n4) {
        float c = ci[i >> 5];
        float4 v = out[i];
        v.x *= c; v.y *= c; v.z *= c; v.w *= c;
        out[i] = v;
    }
}

// ===========================================================================

static inline size_t align256(size_t x) { return (x + 255) & ~(size_t)255; }

extern "C" void kernel_launch(void* const* d_in, const int* in_sizes, int n_in,
                              void* d_out, int out_size, void* d_ws, size_t ws_size,
                              hipStream_t stream) {
    const float* weight = (const float*)d_in[0];
    const float* cj     = (const float*)d_in[1];
    const float* ci     = (const float*)d_in[2];
    const int*   src    = (const int*)d_in[3];
    const int*   dst    = (const int*)d_in[4];
    float* out = (float*)d_out;

    const int N = in_sizes[1];             // cj is [N,1]
    const int E = in_sizes[3];

    const int NBIN  = (N + BINW - 1) >> BINSHIFT;
    const int NTILE = (E + TB - 1) / TB;

    // --- main-path workspace layout ---
    size_t o_feat = 0;                                            // N*FEAT bf16
    size_t o_pair = align256(o_feat + (size_t)N * FEAT * 2);      // E u32
    size_t o_cnt  = align256(o_pair + (size_t)E * 4);             // NTILE*NBIN int
    size_t o_base = align256(o_cnt + (size_t)NTILE * NBIN * 4);   // NTILE*NBIN int
    size_t o_tot  = align256(o_base + (size_t)NTILE * NBIN * 4);  // NBIN int
    size_t o_bs   = align256(o_tot + (size_t)NBIN * 4);           // NBIN+1 int
    size_t o_off  = align256(o_bs + (size_t)(NBIN + 1) * 4);      // N+1 int
    size_t need_new = o_off + (size_t)(N + 1) * 4;

    if (ws_size >= need_new && NBIN <= MAXBIN && NTILE <= MAXTILE &&
        N <= (1 << 17) && out_size >= E) {
        char* ws = (char*)d_ws;
        unsigned short* feat16 = (unsigned short*)(ws + o_feat);
        unsigned* pair   = (unsigned*)(ws + o_pair);
        int* cnt         = (int*)(ws + o_cnt);
        int* base_local  = (int*)(ws + o_base);
        int* binTot      = (int*)(ws + o_tot);
        int* binStart    = (int*)(ws + o_bs);
        int* offsets     = (int*)(ws + o_off);

        convert_kernel<<<(N * (FEAT / 8) + 255) / 256, 256, 0, stream>>>(
            weight, cj, feat16, N);
        hist_bins_kernel<<<NTILE, 256, 0, stream>>>(dst, cnt, E, NBIN);
        bin_scan_kernel<<<NBIN, MAXTILE, 0, stream>>>(cnt, base_local, binTot, NBIN, NTILE);
        scan_tot_kernel<<<1, 1024, 0, stream>>>(binTot, binStart, NBIN);
        scatter_pairs_kernel<<<NTILE, 256, 0, stream>>>(src, dst, base_local, binStart,
                                                        pair, E, NBIN);
        fine_sort_kernel<<<NBIN, 256, 0, stream>>>(pair, (unsigned*)out, binStart,
                                                   offsets, N, E);
        long threads = (long)N * 64;
        gather_kernel<<<(int)((threads + 255) / 256), 256, 0, stream>>>(
            feat16, ci, offsets, (const int*)pair, out, N);
        return;
    }

    // --- mid tier: per-node CSR path ---
    const int NB = (N + 255) / 256;
    size_t m_off = 0;                                              // (N+1) int
    size_t m_cur = align256(m_off + (size_t)(N + 1) * 4);          // N int
    size_t m_bsm = align256(m_cur + (size_t)N * 4);                // 512 int
    size_t m_src = align256(m_bsm + 512 * 4);                      // E int
    size_t m_ft  = align256(m_src + (size_t)E * 4);                // N*FEAT bf16
    size_t need_mid = m_ft + (size_t)N * FEAT * 2;

    if (ws_size >= need_mid && NB <= 512) {
        char* ws = (char*)d_ws;
        int* offsets    = (int*)(ws + m_off);
        int* cursor     = (int*)(ws + m_cur);
        int* bsum       = (int*)(ws + m_bsm);
        int* src_sorted = (int*)(ws + m_src);
        unsigned short* feat16 = (unsigned short*)(ws + m_ft);

        zero_ints_kernel<<<NB, 256, 0, stream>>>(cursor, N);
        {
            long T = (long)N * (FEAT / 8);
            if ((long)E > T) T = E;
            convert_hist_kernel<<<(int)((T + 255) / 256), 256, 0, stream>>>(
                weight, cj, dst, cursor, feat16, N, E);
        }
        block_sum_kernel<<<NB, 256, 0, stream>>>(cursor, bsum, N);
        scan_bsum_kernel<<<1, 512, 0, stream>>>(bsum, NB);
        scan_counts_kernel<<<NB, 256, 0, stream>>>(cursor, bsum, offsets, cursor, N, E);
        bucket_kernel<<<(E + 255) / 256, 256, 0, stream>>>(src, dst, cursor, src_sorted, E);
        long threads = (long)N * 64;
        gather_kernel<<<(int)((threads + 255) / 256), 256, 0, stream>>>(
            feat16, ci, offsets, src_sorted, out, N);
        return;
    }

    // --- last tier: atomics ---
    const int total = N * FEAT;
    const int n4 = total >> 2;
    gcmc_zero_kernel<<<(n4 + 255) / 256, 256, 0, stream>>>((float4*)out, n4);
    const long threads = (long)E * 32;
    gcmc_scatter_kernel<<<(int)((threads + 255) / 256), 256, 0, stream>>>(
        weight, cj, src, dst, out, E);
    gcmc_scale_kernel<<<(n4 + 255) / 256, 256, 0, stream>>>((float4*)out, ci, n4);
}

// Round 9
// 131.419 us; speedup vs baseline: 10.5139x; 1.0054x over previous
//
#include <hip/hip_runtime.h>
#include <hip/hip_bf16.h>

#define FEAT 128
#define BINW 128            // nodes per coarse bin (power of 2)
#define BINSHIFT 7
#define MAXBIN 1024
#define MAXTILE 1024        // bin_scan handles up to 1024 tiles
#define FS_CAP 4096         // fine_sort LDS staging capacity (edges per bin)

__device__ __forceinline__ unsigned short f2b(float f) {
    __hip_bfloat16 h = __float2bfloat16(f);   // RNE
    return *reinterpret_cast<unsigned short*>(&h);
}
__device__ __forceinline__ float b2f_lo(unsigned u) {   // low ushort -> f32
    unsigned x = u << 16;
    float f;
    __builtin_memcpy(&f, &x, 4);
    return f;
}
__device__ __forceinline__ float b2f_hi(unsigned u) {   // high ushort -> f32
    unsigned x = u & 0xFFFF0000u;
    float f;
    __builtin_memcpy(&f, &x, 4);
    return f;
}
__device__ __forceinline__ unsigned int pack2(float lo, float hi) {
    return (unsigned int)f2b(lo) | ((unsigned int)f2b(hi) << 16);
}

// ===========================================================================
// MAIN PATH: two-level binning (all atomics LDS-scope) + per-node gather
// ===========================================================================

// K1: fused. Each tile-block: (a) its share of feat16 = bf16(weight*cj),
//     (b) LDS histogram of its tb edges' coarse bins -> cnt[tile][bin].
__global__ void convert_hist_bins_kernel(const float* __restrict__ weight,
                                         const float* __restrict__ cj,
                                         const int* __restrict__ dst,
                                         unsigned short* __restrict__ feat16,
                                         int* __restrict__ cnt,
                                         int N, int E, int NBIN, int tb, int ipt) {
    __shared__ int h[MAXBIN];
    int tile = blockIdx.x;
    for (int b = threadIdx.x; b < NBIN; b += 256) h[b] = 0;
    __syncthreads();

    // convert share: ipt uint4-items (8 bf16 feats each) per thread
    int NC = N * (FEAT / 8);
    int cbase = tile * 256 * ipt;
    for (int j = 0; j < ipt; ++j) {
        int i = cbase + j * 256 + threadIdx.x;
        if (i < NC) {
            int row = i >> 4;
            int seg = i & 15;
            float c = cj[row];
            const float4* p = reinterpret_cast<const float4*>(
                weight + (size_t)row * FEAT + seg * 8);
            float4 a = p[0], b4 = p[1];
            uint4 o;
            o.x = pack2(a.x * c, a.y * c);
            o.y = pack2(a.z * c, a.w * c);
            o.z = pack2(b4.x * c, b4.y * c);
            o.w = pack2(b4.z * c, b4.w * c);
            *reinterpret_cast<uint4*>(feat16 + (size_t)i * 8) = o;
        }
    }

    // histogram share
    int e0 = tile * tb;
    int iters = tb >> 8;
    for (int i = 0; i < iters; ++i) {
        int e = e0 + i * 256 + threadIdx.x;
        if (e < E) atomicAdd(&h[dst[e] >> BINSHIFT], 1);
    }
    __syncthreads();
    for (int b = threadIdx.x; b < NBIN; b += 256) cnt[(size_t)tile * NBIN + b] = h[b];
}

// K2a: one block per bin: exclusive scan of cnt[*][bin] over tiles ->
//      base_local[tile][bin]; also binTot[bin]. NBIN-way parallel.
__global__ void bin_scan_kernel(const int* __restrict__ cnt, int* __restrict__ base_local,
                                int* __restrict__ binTot, int NBIN, int NTILE) {
    __shared__ int s[MAXTILE];
    int b = blockIdx.x;
    int t = threadIdx.x;              // block = 1024 = MAXTILE
    int v = (t < NTILE) ? cnt[(size_t)t * NBIN + b] : 0;
    s[t] = v;
    __syncthreads();
    for (int off = 1; off < MAXTILE; off <<= 1) {
        int u = (t >= off) ? s[t - off] : 0;
        __syncthreads();
        s[t] += u;
        __syncthreads();
    }
    if (t < NTILE) base_local[(size_t)t * NBIN + b] = s[t] - v;   // exclusive
    if (t == MAXTILE - 1) binTot[b] = s[t];                       // inclusive total
}

// K2b: single-block exclusive scan of binTot[NBIN] -> binStart[0..NBIN]
__global__ void scan_tot_kernel(const int* __restrict__ binTot, int* __restrict__ binStart,
                                int NBIN) {
    __shared__ int s[1024];
    int t = threadIdx.x;
    int v = (t < NBIN) ? binTot[t] : 0;
    s[t] = v;
    __syncthreads();
    for (int off = 1; off < 1024; off <<= 1) {
        int u = (t >= off) ? s[t - off] : 0;
        __syncthreads();
        s[t] += u;
        __syncthreads();
    }
    if (t < NBIN) binStart[t] = s[t] - v;
    if (t == NBIN - 1) binStart[NBIN] = s[t];
}

// K3: scatter packed (src | local_dst<<17) into coarse-bin-grouped order.
// LDS cursors only; global writes land in NBIN contiguous regions.
__global__ void scatter_pairs_kernel(const int* __restrict__ src, const int* __restrict__ dst,
                                     const int* __restrict__ base_local,
                                     const int* __restrict__ binStart,
                                     unsigned* __restrict__ pair,
                                     int E, int NBIN, int tb) {
    __shared__ int base_l[MAXBIN];
    __shared__ int cur[MAXBIN];
    int tile = blockIdx.x;
    for (int b = threadIdx.x; b < NBIN; b += 256) {
        base_l[b] = binStart[b] + base_local[(size_t)tile * NBIN + b];
        cur[b] = 0;
    }
    __syncthreads();
    int e0 = tile * tb;
    int iters = tb >> 8;
    for (int i = 0; i < iters; ++i) {
        int e = e0 + i * 256 + threadIdx.x;
        if (e < E) {
            int d = dst[e];
            int b = d >> BINSHIFT;
            int pos = atomicAdd(&cur[b], 1);
            pair[base_l[b] + pos] = (unsigned)src[e] | ((unsigned)(d & (BINW - 1)) << 17);
        }
    }
}

// K4: per-bin fine counting sort. One 256-thread block per bin (~2K edges,
// 128 local nodes). Common case: stages the segment in LDS (<= FS_CAP edges);
// oversize bins fall back to staging through `tmp` (= d_out as scratch, fully
// rewritten by the gather afterwards). Emits per-node CSR offsets and writes
// src values back into `pair` grouped by node. All atomics LDS-scope.
__global__ void fine_sort_kernel(unsigned* __restrict__ pair,
                                 unsigned* __restrict__ tmp,
                                 const int* __restrict__ binStart,
                                 int* __restrict__ offsets,
                                 int N, int E) {
    __shared__ int cnt[BINW];
    __shared__ int sbase[BINW];
    __shared__ unsigned stage[FS_CAP];
    int bin = blockIdx.x;
    int t = threadIdx.x;
    if (t < BINW) cnt[t] = 0;
    __syncthreads();
    int start = binStart[bin];
    int end   = binStart[bin + 1];
    bool lds_ok = (end - start) <= FS_CAP;

    if (lds_ok) {
        for (int k = start + t; k < end; k += 256) {
            unsigned p = pair[k];
            stage[k - start] = p;
            atomicAdd(&cnt[p >> 17], 1);
        }
    } else {
        for (int k = start + t; k < end; k += 256) {
            unsigned p = pair[k];
            tmp[k] = p;
            atomicAdd(&cnt[p >> 17], 1);
        }
    }
    __syncthreads();
    int mine = (t < BINW) ? cnt[t] : 0;
    if (t < BINW) sbase[t] = mine;
    __syncthreads();
    for (int d = 1; d < BINW; d <<= 1) {     // Hillis-Steele inclusive scan
        int v = 0;
        if (t < BINW && t >= d) v = sbase[t - d];
        __syncthreads();
        if (t < BINW) sbase[t] += v;
        __syncthreads();
    }
    if (t < BINW) {
        int excl = sbase[t] - mine;
        int node = (bin << BINSHIFT) + t;
        if (node < N) offsets[node] = start + excl;
        sbase[t] = start + excl;             // absolute base per local node
        cnt[t] = 0;                          // reuse as cursor
    }
    if (bin == 0 && t == 0) offsets[N] = E;
    __syncthreads();
    if (lds_ok) {
        for (int k = start + t; k < end; k += 256) {
            unsigned p = stage[k - start];
            int ld = p >> 17;
            int pos = atomicAdd(&cnt[ld], 1);
            pair[sbase[ld] + pos] = p & 0x1FFFF;
        }
    } else {
        for (int k = start + t; k < end; k += 256) {
            unsigned p = tmp[k];
            int ld = p >> 17;
            int pos = atomicAdd(&cnt[ld], 1);
            pair[sbase[ld] + pos] = p & 0x1FFFF;
        }
    }
}

// K5: one 64-lane wave per node, split as 4x16-lane groups; each group takes
// every 4th edge; each lane loads 16 B (8 bf16 feats) per edge. unroll 4 ->
// up to 4 rows in flight per group (16 per wave). Reduce with two shfl_xor
// levels; quarter 0 writes 32 B/lane.
__global__ void gather_kernel(const unsigned short* __restrict__ feat16,
                              const float* __restrict__ ci,
                              const int* __restrict__ offsets,
                              const int* __restrict__ src_sorted,
                              float* __restrict__ out, int N) {
    int gt = blockIdx.x * blockDim.x + threadIdx.x;
    int node = gt >> 6;
    if (node >= N) return;
    int lane = gt & 63;
    int fi   = (lane & 15) << 3;         // feature offset (0,8,...,120)
    int q    = lane >> 4;                // quarter 0..3
    int start = offsets[node];
    int end   = offsets[node + 1];
    float acc[8] = {0.f, 0.f, 0.f, 0.f, 0.f, 0.f, 0.f, 0.f};
    #pragma unroll 4
    for (int k = start + q; k < end; k += 4) {
        int s = src_sorted[k];
        uint4 u = *reinterpret_cast<const uint4*>(feat16 + ((size_t)s << 7) + fi);
        acc[0] += b2f_lo(u.x); acc[1] += b2f_hi(u.x);
        acc[2] += b2f_lo(u.y); acc[3] += b2f_hi(u.y);
        acc[4] += b2f_lo(u.z); acc[5] += b2f_hi(u.z);
        acc[6] += b2f_lo(u.w); acc[7] += b2f_hi(u.w);
    }
    #pragma unroll
    for (int j = 0; j < 8; ++j) {
        acc[j] += __shfl_xor(acc[j], 16);
        acc[j] += __shfl_xor(acc[j], 32);
    }
    if (q == 0) {
        float c = ci[node];
        float4 v0 = make_float4(acc[0] * c, acc[1] * c, acc[2] * c, acc[3] * c);
        float4 v1 = make_float4(acc[4] * c, acc[5] * c, acc[6] * c, acc[7] * c);
        float* o = out + ((size_t)node << 7) + fi;
        *reinterpret_cast<float4*>(o)     = v0;
        *reinterpret_cast<float4*>(o + 4) = v1;
    }
}

// ===========================================================================
// MID TIER (verified): per-node CSR + bf16 gather
// ===========================================================================

__global__ void zero_ints_kernel(int* __restrict__ p, int n) {
    int i = blockIdx.x * blockDim.x + threadIdx.x;
    if (i < n) p[i] = 0;
}

__global__ void convert_hist_kernel(const float* __restrict__ weight,
                                    const float* __restrict__ cj,
                                    const int* __restrict__ dst,
                                    int* __restrict__ counts,
                                    unsigned short* __restrict__ feat16,
                                    int N, int E) {
    int i = blockIdx.x * blockDim.x + threadIdx.x;
    int NC = N * (FEAT / 8);
    if (i < NC) {
        int row = i >> 4;
        int seg = i & 15;
        float c = cj[row];
        const float4* p = reinterpret_cast<const float4*>(weight + (size_t)row * FEAT + seg * 8);
        float4 a = p[0], b = p[1];
        uint4 o;
        o.x = pack2(a.x * c, a.y * c);
        o.y = pack2(a.z * c, a.w * c);
        o.z = pack2(b.x * c, b.y * c);
        o.w = pack2(b.z * c, b.w * c);
        *reinterpret_cast<uint4*>(feat16 + (size_t)i * 8) = o;
    }
    if (i < E) atomicAdd(&counts[dst[i]], 1);
}

__global__ void block_sum_kernel(const int* __restrict__ counts, int* __restrict__ bsum, int N) {
    __shared__ int s[256];
    int i = blockIdx.x * 256 + threadIdx.x;
    s[threadIdx.x] = (i < N) ? counts[i] : 0;
    __syncthreads();
    for (int off = 128; off > 0; off >>= 1) {
        if (threadIdx.x < off) s[threadIdx.x] += s[threadIdx.x + off];
        __syncthreads();
    }
    if (threadIdx.x == 0) bsum[blockIdx.x] = s[0];
}

__global__ void scan_bsum_kernel(int* __restrict__ bsum, int nb) {
    __shared__ int s[512];
    int t = threadIdx.x;
    int mine = (t < nb) ? bsum[t] : 0;
    s[t] = mine;
    __syncthreads();
    for (int off = 1; off < 512; off <<= 1) {
        int v = (t >= off) ? s[t - off] : 0;
        __syncthreads();
        s[t] += v;
        __syncthreads();
    }
    if (t < nb) bsum[t] = s[t] - mine;
}

__global__ void scan_counts_kernel(const int* __restrict__ counts, const int* __restrict__ bsum,
                                   int* __restrict__ offsets, int* __restrict__ cursor,
                                   int N, int E) {
    __shared__ int s[256];
    int t = threadIdx.x;
    int i = blockIdx.x * 256 + t;
    int mine = (i < N) ? counts[i] : 0;
    s[t] = mine;
    __syncthreads();
    for (int off = 1; off < 256; off <<= 1) {
        int v = (t >= off) ? s[t - off] : 0;
        __syncthreads();
        s[t] += v;
        __syncthreads();
    }
    if (i < N) {
        int o = bsum[blockIdx.x] + s[t] - mine;
        offsets[i] = o;
        cursor[i] = o;
    }
    if (i == 0 && blockIdx.x == 0) offsets[N] = E;
}

__global__ void bucket_kernel(const int* __restrict__ src, const int* __restrict__ dst,
                              int* __restrict__ cursor,
                              int* __restrict__ src_sorted, int E) {
    int i = blockIdx.x * blockDim.x + threadIdx.x;
    if (i < E) {
        int pos = atomicAdd(&cursor[dst[i]], 1);
        src_sorted[pos] = src[i];
    }
}

// ===========================================================================
// LAST TIER (round-1 verified): float atomics
// ===========================================================================

__global__ void gcmc_zero_kernel(float4* __restrict__ out, int n4) {
    int i = blockIdx.x * blockDim.x + threadIdx.x;
    if (i < n4) out[i] = make_float4(0.f, 0.f, 0.f, 0.f);
}

__global__ void gcmc_scatter_kernel(const float* __restrict__ weight,
                                    const float* __restrict__ cj,
                                    const int* __restrict__ src,
                                    const int* __restrict__ dst,
                                    float* __restrict__ out,
                                    int n_edges) {
    int t = blockIdx.x * blockDim.x + threadIdx.x;
    int e = t >> 5;
    int f = (t & 31) << 2;
    if (e >= n_edges) return;
    int s = src[e];
    int d = dst[e];
    float c = cj[s];
    const float4 w = *reinterpret_cast<const float4*>(weight + (size_t)s * FEAT + f);
    float* o = out + (size_t)d * FEAT + f;
    unsafeAtomicAdd(o + 0, w.x * c);
    unsafeAtomicAdd(o + 1, w.y * c);
    unsafeAtomicAdd(o + 2, w.z * c);
    unsafeAtomicAdd(o + 3, w.w * c);
}

__global__ void gcmc_scale_kernel(float4* __restrict__ out,
                                  const float* __restrict__ ci, int n4) {
    int i = blockIdx.x * blockDim.x + threadIdx.x;
    if (i < n4) {
        float c = ci[i >> 5];
        float4 v = out[i];
        v.x *= c; v.y *= c; v.z *= c; v.w *= c;
        out[i] = v;
    }
}

// ===========================================================================

static inline size_t align256(size_t x) { return (x + 255) & ~(size_t)255; }

extern "C" void kernel_launch(void* const* d_in, const int* in_sizes, int n_in,
                              void* d_out, int out_size, void* d_ws, size_t ws_size,
                              hipStream_t stream) {
    const float* weight = (const float*)d_in[0];
    const float* cj     = (const float*)d_in[1];
    const float* ci     = (const float*)d_in[2];
    const int*   src    = (const int*)d_in[3];
    const int*   dst    = (const int*)d_in[4];
    float* out = (float*)d_out;

    const int N = in_sizes[1];             // cj is [N,1]
    const int E = in_sizes[3];

    const int NBIN = (N + BINW - 1) >> BINSHIFT;

    // Try TB=2048 (best CU coverage), fall back to TB=8192, then mid tier.
    for (int tb = 2048; tb <= 8192; tb *= 4) {
        const int NTILE = (E + tb - 1) / tb;
        if (NTILE > MAXTILE) continue;

        size_t o_feat = 0;                                            // N*FEAT bf16
        size_t o_pair = align256(o_feat + (size_t)N * FEAT * 2);      // E u32
        size_t o_cnt  = align256(o_pair + (size_t)E * 4);             // NTILE*NBIN int
        size_t o_base = align256(o_cnt + (size_t)NTILE * NBIN * 4);   // NTILE*NBIN int
        size_t o_tot  = align256(o_base + (size_t)NTILE * NBIN * 4);  // NBIN int
        size_t o_bs   = align256(o_tot + (size_t)NBIN * 4);           // NBIN+1 int
        size_t o_off  = align256(o_bs + (size_t)(NBIN + 1) * 4);      // N+1 int
        size_t need   = o_off + (size_t)(N + 1) * 4;

        if (ws_size < need || NBIN > MAXBIN || N > (1 << 17) || out_size < E) continue;

        char* ws = (char*)d_ws;
        unsigned short* feat16 = (unsigned short*)(ws + o_feat);
        unsigned* pair   = (unsigned*)(ws + o_pair);
        int* cnt         = (int*)(ws + o_cnt);
        int* base_local  = (int*)(ws + o_base);
        int* binTot      = (int*)(ws + o_tot);
        int* binStart    = (int*)(ws + o_bs);
        int* offsets     = (int*)(ws + o_off);

        const int NC  = N * (FEAT / 8);
        const int ipt = (NC + NTILE * 256 - 1) / (NTILE * 256);

        convert_hist_bins_kernel<<<NTILE, 256, 0, stream>>>(
            weight, cj, dst, feat16, cnt, N, E, NBIN, tb, ipt);
        bin_scan_kernel<<<NBIN, MAXTILE, 0, stream>>>(cnt, base_local, binTot, NBIN, NTILE);
        scan_tot_kernel<<<1, 1024, 0, stream>>>(binTot, binStart, NBIN);
        scatter_pairs_kernel<<<NTILE, 256, 0, stream>>>(src, dst, base_local, binStart,
                                                        pair, E, NBIN, tb);
        fine_sort_kernel<<<NBIN, 256, 0, stream>>>(pair, (unsigned*)out, binStart,
                                                   offsets, N, E);
        long threads = (long)N * 64;
        gather_kernel<<<(int)((threads + 255) / 256), 256, 0, stream>>>(
            feat16, ci, offsets, (const int*)pair, out, N);
        return;
    }

    // --- mid tier: per-node CSR path ---
    const int NB = (N + 255) / 256;
    size_t m_off = 0;                                              // (N+1) int
    size_t m_cur = align256(m_off + (size_t)(N + 1) * 4);          // N int
    size_t m_bsm = align256(m_cur + (size_t)N * 4);                // 512 int
    size_t m_src = align256(m_bsm + 512 * 4);                      // E int
    size_t m_ft  = align256(m_src + (size_t)E * 4);                // N*FEAT bf16
    size_t need_mid = m_ft + (size_t)N * FEAT * 2;

    if (ws_size >= need_mid && NB <= 512) {
        char* ws = (char*)d_ws;
        int* offsets    = (int*)(ws + m_off);
        int* cursor     = (int*)(ws + m_cur);
        int* bsum       = (int*)(ws + m_bsm);
        int* src_sorted = (int*)(ws + m_src);
        unsigned short* feat16 = (unsigned short*)(ws + m_ft);

        zero_ints_kernel<<<NB, 256, 0, stream>>>(cursor, N);
        {
            long T = (long)N * (FEAT / 8);
            if ((long)E > T) T = E;
            convert_hist_kernel<<<(int)((T + 255) / 256), 256, 0, stream>>>(
                weight, cj, dst, cursor, feat16, N, E);
        }
        block_sum_kernel<<<NB, 256, 0, stream>>>(cursor, bsum, N);
        scan_bsum_kernel<<<1, 512, 0, stream>>>(bsum, NB);
        scan_counts_kernel<<<NB, 256, 0, stream>>>(cursor, bsum, offsets, cursor, N, E);
        bucket_kernel<<<(E + 255) / 256, 256, 0, stream>>>(src, dst, cursor, src_sorted, E);
        long threads = (long)N * 64;
        gather_kernel<<<(int)((threads + 255) / 256), 256, 0, stream>>>(
            feat16, ci, offsets, src_sorted, out, N);
        return;
    }

    // --- last tier: atomics ---
    const int total = N * FEAT;
    const int n4 = total >> 2;
    gcmc_zero_kernel<<<(n4 + 255) / 256, 256, 0, stream>>>((float4*)out, n4);
    const long threads = (long)E * 32;
    gcmc_scatter_kernel<<<(int)((threads + 255) / 256), 256, 0, stream>>>(
        weight, cj, src, dst, out, E);
    gcmc_scale_kernel<<<(n4 + 255) / 256, 256, 0, stream>>>((float4*)out, ci, n4);
}